// Round 7
// baseline (189.130 us; speedup 1.0000x reference)
//
#include <hip/hip_runtime.h>

typedef unsigned short u16;
typedef u16   u16x8 __attribute__((ext_vector_type(8)));
typedef __bf16 bf16x8 __attribute__((ext_vector_type(8)));
typedef float f32x4 __attribute__((ext_vector_type(4)));
typedef float f32x2 __attribute__((ext_vector_type(2)));
typedef _Float16 f16x4 __attribute__((ext_vector_type(4)));
typedef _Float16 f16x8 __attribute__((ext_vector_type(8)));
typedef unsigned u32x2 __attribute__((ext_vector_type(2)));
typedef unsigned u32x4 __attribute__((ext_vector_type(4)));

__device__ __forceinline__ u16 f2b(float f){ __bf16 h=(__bf16)f; return __builtin_bit_cast(u16,h); }

__device__ __forceinline__ float ex2(float x){
#if __has_builtin(__builtin_amdgcn_exp2f)
  return __builtin_amdgcn_exp2f(x);      // bare v_exp_f32, no libm range fixup
#else
  float r; asm("v_exp_f32 %0, %1" : "=v"(r) : "v"(x)); return r;
#endif
}

__device__ __forceinline__ f32x4 mfma16(u16x8 a, u16x8 b, f32x4 c){
  return __builtin_amdgcn_mfma_f32_16x16x32_bf16(
      __builtin_bit_cast(bf16x8,a), __builtin_bit_cast(bf16x8,b), c, 0,0,0);
}

__device__ __forceinline__ f32x4 mfma32h(f16x8 a, f16x8 b, f32x4 c){
  return __builtin_amdgcn_mfma_f32_16x16x32_f16(a, b, c, 0,0,0);
}

__device__ __forceinline__ void gl2lds16(const u16* g, u16* l){
  __builtin_amdgcn_global_load_lds((const __attribute__((address_space(1))) void*)g,
                                   (__attribute__((address_space(3))) void*)l, 16, 0, 0);
}

// ------------- prep: LN (blocks 0..4095) + weight transpose (4096..5119) -------------
// ln: fp32 [4096,1024] -> bf16 xn. wtrans: fp32 [R][C] -> bf16 [C][R] for 3 weights.
__global__ __launch_bounds__(256) void prep_kernel(const float* __restrict__ x,
    const float* __restrict__ gamma, const float* __restrict__ beta, u16* __restrict__ xn,
    const float* __restrict__ wq, const float* __restrict__ wkv, const float* __restrict__ wout,
    u16* __restrict__ wqkvt, u16* __restrict__ woutt){
  __shared__ float tile[64][65];
  __shared__ float red[8];
  const int bid=blockIdx.x, t=threadIdx.x;
  if(bid<4096){
    const int row=bid;
    const float4 v = ((const float4*)(x + (size_t)row*1024))[t];
    float s  = v.x+v.y+v.z+v.w;
    float sq = v.x*v.x+v.y*v.y+v.z*v.z+v.w*v.w;
    for (int m=1;m<64;m<<=1){ s += __shfl_xor(s,m); sq += __shfl_xor(sq,m); }
    const int w=t>>6, l=t&63;
    if(l==0){ red[w]=s; red[4+w]=sq; }
    __syncthreads();
    const float S  = red[0]+red[1]+red[2]+red[3];
    const float SQ = red[4]+red[5]+red[6]+red[7];
    const float mu = S*(1.f/1024.f);
    const float var= SQ*(1.f/1024.f)-mu*mu;
    const float rs = rsqrtf(var+1e-5f);
    const float4 g4=((const float4*)gamma)[t], b4=((const float4*)beta)[t];
    u16 o0=f2b((v.x-mu)*rs*g4.x+b4.x);
    u16 o1=f2b((v.y-mu)*rs*g4.y+b4.y);
    u16 o2=f2b((v.z-mu)*rs*g4.z+b4.z);
    u16 o3=f2b((v.w-mu)*rs*g4.w+b4.w);
    uint2 p; p.x=(unsigned)o0|((unsigned)o1<<16); p.y=(unsigned)o2|((unsigned)o3<<16);
    ((uint2*)(xn + (size_t)row*1024))[t]=p;
    return;
  }
  const int wb=bid-4096;
  const int bx=wb&63, by=wb>>6;
  const float* in; u16* out; int C, cxx;
  if(bx<16){ in=wq;  out=wqkvt;           C=1024; cxx=bx; }
  else if(bx<48){ in=wkv; out=wqkvt+1024*1024; C=2048; cxx=bx-16; }
  else { in=wout; out=woutt;             C=1024; cxx=bx-48; }
  const int R=1024;
  const int c0=cxx*64, r0=by*64;
  {
    const int r=t>>2, cc=t&3;
    const float* gp = in + (size_t)(r0+r)*C + c0 + cc*16;
    #pragma unroll
    for(int i=0;i<4;i++){
      float4 f=((const float4*)gp)[i];
      tile[r][cc*16+i*4+0]=f.x; tile[r][cc*16+i*4+1]=f.y;
      tile[r][cc*16+i*4+2]=f.z; tile[r][cc*16+i*4+3]=f.w;
    }
  }
  __syncthreads();
  const int c=t>>2, rc=t&3;
  u16x8 a,b;
  #pragma unroll
  for(int i=0;i<8;i++) a[i]=f2b(tile[rc*16+i][c]);
  #pragma unroll
  for(int i=0;i<8;i++) b[i]=f2b(tile[rc*16+8+i][c]);
  u16* op = out + (size_t)(c0+c)*R + r0 + rc*16;
  *(u16x8*)op=a; *(u16x8*)(op+8)=b;
}

// --------------- GEMM: A bf16 [M,K] x Bt bf16 [N,K], tile TM x 128 -------------
// MODE=1: fp32 out + bias.
// MODE=2: qkv split. col<1024 -> outQ bf16 row-major (scaled by `scale`).
//         1024..2047 -> outK bf16 packed per-head [b][h][j 2048][d 64].
//         2048..3071 -> outV fp16 packed [b][h][j/32][(j>>3)&3][d 64][j&7]
//                       (B-fragment layout for mfma_f32_16x16x32_f16 in attn PV).
template<int MODE,int TM>
__global__ __launch_bounds__(256) void gemm_bt_kernel(const u16* __restrict__ A,
    const u16* __restrict__ Bt, u16* __restrict__ outQ, u16* __restrict__ outK,
    u16* __restrict__ outV, float* __restrict__ outF, const float* __restrict__ bias,
    float scale, int M, int N, int K){
  constexpr int MT = TM/32;           // acc m-tiles per wave
  __shared__ u16 As[TM*64];
  __shared__ u16 Bs[128*64];
  const int t=threadIdx.x, w=t>>6, l=t&63, qd=l>>4, ln=l&15;
  const int m0=blockIdx.y*TM, n0=blockIdx.x*128;
  const int wm=(w>>1)*(TM/2), wn=(w&1)*64;
  f32x4 acc[MT][4] = {};
  const int nK = K>>6;
  for(int kt=0; kt<nK; kt++){
    const int k0=kt*64;
    #pragma unroll
    for(int p=0;p<MT;p++){
      const int cid=p*256+t, r=cid>>3, pc=cid&7, g=pc^(r&7);
      gl2lds16(A + (size_t)(m0+r)*K + k0 + g*8, &As[(p*256 + (t&192))*8]);
    }
    #pragma unroll
    for(int p=0;p<4;p++){
      const int cid=p*256+t, r=cid>>3, pc=cid&7, g=pc^(r&7);
      gl2lds16(Bt + (size_t)(n0+r)*K + k0 + g*8, &Bs[(p*256 + (t&192))*8]);
    }
    __syncthreads();
    #pragma unroll
    for(int ks=0;ks<2;ks++){
      u16x8 af[MT], bf[4];
      #pragma unroll
      for(int mt=0;mt<MT;mt++){
        const int m=wm+mt*16+ln, kc=ks*4+qd, pcc=kc^(m&7);
        af[mt]=*(const u16x8*)&As[m*64 + pcc*8];
      }
      #pragma unroll
      for(int nt=0;nt<4;nt++){
        const int n=wn+nt*16+ln, kc=ks*4+qd, pcc=kc^(n&7);
        bf[nt]=*(const u16x8*)&Bs[n*64 + pcc*8];
      }
      #pragma unroll
      for(int mt=0;mt<MT;mt++)
        #pragma unroll
        for(int nt=0;nt<4;nt++)
          acc[mt][nt]=mfma16(af[mt],bf[nt],acc[mt][nt]);
    }
    __syncthreads();
  }
  if(MODE==1){
    #pragma unroll
    for(int mt=0;mt<MT;mt++)
      #pragma unroll
      for(int rr=0;rr<4;rr++){
        const int row = m0+wm+mt*16+qd*4+rr;
        #pragma unroll
        for(int nt=0;nt<4;nt++){
          const int col = n0+wn+nt*16+ln;
          outF[(size_t)row*N+col]=acc[mt][nt][rr]+bias[col];
        }
      }
  } else if(n0<1024){
    #pragma unroll
    for(int mt=0;mt<MT;mt++)
      #pragma unroll
      for(int rr=0;rr<4;rr++){
        const int row = m0+wm+mt*16+qd*4+rr;
        #pragma unroll
        for(int nt=0;nt<4;nt++)
          outQ[(size_t)row*1024 + n0+wn+nt*16+ln]=f2b(acc[mt][nt][rr]*scale);
      }
  } else if(n0<2048){
    // K packed per-head: head is wave-uniform; d = nt*16+ln
    u16* kp = outK + (size_t)((m0>>11)*16 + ((n0-1024+wn)>>6))*131072;
    const int jb = (m0&2047) + wm;
    #pragma unroll
    for(int mt=0;mt<MT;mt++)
      #pragma unroll
      for(int rr=0;rr<4;rr++){
        const int j = jb + mt*16 + qd*4 + rr;
        #pragma unroll
        for(int nt=0;nt<4;nt++)
          kp[(size_t)j*64 + nt*16+ln]=f2b(acc[mt][nt][rr]);
      }
  } else {
    // V packed fp16 [j/32][(j>>3)&3][d 64][j&7]: lane writes 4 j-consecutive f16 = uint2
    u16* vpp = outV + (size_t)((m0>>11)*16 + ((n0-2048+wn)>>6))*131072;
    const int jb = (m0&2047) + wm;
    #pragma unroll
    for(int mt=0;mt<MT;mt++){
      const int j = jb + mt*16 + qd*4;                  // + rr (0..3)
      const int grp = (j>>5)*4 + ((j>>3)&3);            // wave-uniform per (mt,qd)
      const int sub = j&7;                              // = (qd&1)*4
      #pragma unroll
      for(int nt=0;nt<4;nt++){
        const auto lo=__builtin_amdgcn_cvt_pkrtz(acc[mt][nt][0],acc[mt][nt][1]);
        const auto hi=__builtin_amdgcn_cvt_pkrtz(acc[mt][nt][2],acc[mt][nt][3]);
        uint2 w2; w2.x=__builtin_bit_cast(unsigned,lo); w2.y=__builtin_bit_cast(unsigned,hi);
        *(uint2*)&vpp[(size_t)(grp*64 + nt*16+ln)*8 + sub] = w2;
      }
    }
  }
}

// ------------------ flash attention (S^T, fixed-base softmax) ------------------
// Q bf16 [b,2048,1024] (scale*log2e folded), Kp bf16 [b,h,2048,64] packed,
// Vp fp16 [b,h,j/32,(j>>3)&3,d 64,j&7], O bf16 [b,2048,1024].
// Round-6: small-block restructure for latency hiding.
//  - 128-thread blocks (2 waves x 32 q-rows), grid (32,16,2)=1024 -> 4 blocks/CU:
//    4 INDEPENDENT barrier domains per CU (was 1x8-wave lockstep at 18% occ).
//  - V no longer staged in LDS: per-wave direct global->reg loads (V is L2-resident,
//    pack layout = per-lane contiguous 16B). Halves LDS-pipe demand; LDS = K
//    double-buffer only (32KB) so 4 blocks fit.
//  - V loads issued right after the barrier, consumed after QK (~400cy cover for
//    ~200cy L2 latency); stage K(t+1) issued AFTER them so the compiler's own
//    counted vmcnt for vv leaves the staging in flight.
//  - multi-wave gl2lds hazard: per-wave s_waitcnt vmcnt(0) (only own stage(t)
//    outstanding there) BEFORE the raw s_barrier -> after barrier, all waves'
//    DMAs have landed.
__global__ __launch_bounds__(128,2) void attn_kernel(const u16* __restrict__ Q,
    const u16* __restrict__ Kp, const u16* __restrict__ Vp, u16* __restrict__ O){
  __shared__ u16 Ks[2][8192];   // 2x16KB: K tile [128 j][64 d], permuted rows + xor swizzle
  const int qt=blockIdx.x, h=blockIdx.y, bb=blockIdx.z;
  const int t=threadIdx.x, w=t>>6, l=t&63, qd=l>>4, ln=l&15;
  const int q0=qt*64;
  const size_t baseQ=(size_t)bb*2048*1024 + h*64;
  const size_t baseKV=(size_t)(bb*16+h)*131072;
  u16x8 qf[2][2];
  #pragma unroll
  for(int sub=0;sub<2;sub++)
    #pragma unroll
    for(int ks=0;ks<2;ks++)
      qf[sub][ks] = *(const u16x8*)(Q + baseQ + (size_t)(q0+w*32+sub*16+ln)*1024 + ks*32+qd*8);
  f32x4 o_acc[2][4]={};
  f32x4 l_acc[2]={};
  const f16x8 onesB={(_Float16)1.f,(_Float16)1.f,(_Float16)1.f,(_Float16)1.f,
                     (_Float16)1.f,(_Float16)1.f,(_Float16)1.f,(_Float16)1.f};
  const f32x4 zf={0.f,0.f,0.f,0.f};

  // K staging source offsets: row-permutation + xor chunk swizzle (8 chunks/thread)
  int koff[8];
  #pragma unroll
  for(int p=0;p<8;p++){
    const int r=(p*128+t)>>3, g=(t&7)^(r&7);
    const int pr=(r&~31)+((r>>2)&3)*8+((r>>4)&1)*4+(r&3);
    koff[p]=pr*64+g*8;
  }
  auto stageK=[&](int buf,int j0){
    #pragma unroll
    for(int p=0;p<8;p++)
      gl2lds16(Kp + baseKV + (size_t)j0*64 + koff[p], &Ks[buf][(p*128+(t&64))*8]);
  };
  // per-lane V base (element units); vv[a][dt] at + jt*8192 + a*2048 + dt*128
  const u16* Vl = Vp + baseKV + qd*512 + ln*8;

  stageK(0,0);
  for(int jt=0;jt<16;jt++){
    // own stage(t) is the only outstanding vmem here -> drain, then barrier:
    // after the barrier ALL waves' K DMAs have landed and buf[(t+1)&1] is free.
    asm volatile("s_waitcnt vmcnt(0)" ::: "memory");
    asm volatile("s_barrier" ::: "memory");
    // V(t) loads first (oldest), stage K(t+1) after (younger) so compiler's
    // vv waits leave the staging in flight.
    f16x8 vv[4][4];
    const u16* vb = Vl + (size_t)jt*8192;
    #pragma unroll
    for(int a=0;a<4;a++)
      #pragma unroll
      for(int dt=0;dt<4;dt++)
        vv[a][dt]=*(const f16x8*)(vb + a*2048 + dt*128);
    if(jt<15) stageK((jt+1)&1,(jt+1)*128);
    const u16* Kb=&Ks[jt&1][0];
    #pragma unroll
    for(int jh=0;jh<2;jh++){
      // S^T for both q-subtiles; one kf read serves both (LDS amortization)
      f32x4 s[2][4];
      #pragma unroll
      for(int ks=0;ks<2;ks++){
        u16x8 kf[4];
        #pragma unroll
        for(int j4=0;j4<4;j4++)
          kf[j4]=*(const u16x8*)&Kb[((jh*4+j4)*16+ln)*64 + (((ks*4+qd)^(ln&7))*8)];
        __builtin_amdgcn_s_setprio(1);
        #pragma unroll
        for(int j4=0;j4<4;j4++){
          s[0][j4] = ks? mfma16(kf[j4],qf[0][1],s[0][j4]) : mfma16(kf[j4],qf[0][0],zf);
          s[1][j4] = ks? mfma16(kf[j4],qf[1][1],s[1][j4]) : mfma16(kf[j4],qf[1][0],zf);
        }
        __builtin_amdgcn_s_setprio(0);
      }
      // P = exp2(s); V from regs serves both subtiles' PV; l via ones-MFMA
      #pragma unroll
      for(int al=0;al<2;al++){
        const int a=jh*2+al;             // j32 group
        #pragma unroll
        for(int sub=0;sub<2;sub++){
          const int t0=al*2, t1=al*2+1;
          u32x4 pw;
          pw.x=__builtin_bit_cast(unsigned,__builtin_amdgcn_cvt_pkrtz(ex2(s[sub][t0][0]),ex2(s[sub][t0][1])));
          pw.y=__builtin_bit_cast(unsigned,__builtin_amdgcn_cvt_pkrtz(ex2(s[sub][t0][2]),ex2(s[sub][t0][3])));
          pw.z=__builtin_bit_cast(unsigned,__builtin_amdgcn_cvt_pkrtz(ex2(s[sub][t1][0]),ex2(s[sub][t1][1])));
          pw.w=__builtin_bit_cast(unsigned,__builtin_amdgcn_cvt_pkrtz(ex2(s[sub][t1][2]),ex2(s[sub][t1][3])));
          const f16x8 pf=__builtin_bit_cast(f16x8,pw);
          __builtin_amdgcn_s_setprio(1);
          l_acc[sub]=mfma32h(pf,onesB,l_acc[sub]);
          #pragma unroll
          for(int dt=0;dt<4;dt++)
            o_acc[sub][dt]=mfma32h(pf,vv[a][dt],o_acc[sub][dt]);
          __builtin_amdgcn_s_setprio(0);
        }
      }
    }
  }

  // l_acc[sub][rr] = sum_j P (same across ln) -> direct normalize
  #pragma unroll
  for(int sub=0;sub<2;sub++)
    #pragma unroll
    for(int rr=0;rr<4;rr++){
      const float lr=1.f/l_acc[sub][rr];
      const int row=q0+w*32+sub*16+qd*4+rr;
      #pragma unroll
      for(int dt=0;dt<4;dt++)
        O[baseQ + (size_t)row*1024 + dt*16+ln]=f2b(o_acc[sub][dt][rr]*lr);
    }
}

extern "C" void kernel_launch(void* const* d_in, const int* in_sizes, int n_in,
                              void* d_out, int out_size, void* d_ws, size_t ws_size,
                              hipStream_t stream) {
  const float* x     = (const float*)d_in[0];
  const float* w_q   = (const float*)d_in[1];
  const float* w_kv  = (const float*)d_in[2];
  const float* w_out = (const float*)d_in[3];
  const float* b_out = (const float*)d_in[4];
  const float* gamma = (const float*)d_in[5];
  const float* beta  = (const float*)d_in[6];
  float* out = (float*)d_out;

  char* ws=(char*)d_ws;
  size_t off=0;
  u16* xn    =(u16*)(ws+off); off += (size_t)4096*1024*2;
  u16* wqkvt =(u16*)(ws+off); off += (size_t)3072*1024*2;
  u16* woutt =(u16*)(ws+off); off += (size_t)1024*1024*2;
  u16* qb    =(u16*)(ws+off); off += (size_t)4096*1024*2;
  u16* kpb   =(u16*)(ws+off); off += (size_t)4096*1024*2;
  u16* vpb   =(u16*)(ws+off); off += (size_t)4096*1024*2;
  u16* ob    =(u16*)(ws+off); off += (size_t)4096*1024*2;

  prep_kernel<<<5120,256,0,stream>>>(x,gamma,beta,xn,w_q,w_kv,w_out,wqkvt,woutt);

  const float SCALE_Q = 0.125f*1.4426950408889634f; // 1/sqrt(64) * log2(e)
  gemm_bt_kernel<2,128><<<dim3(24,32),256,0,stream>>>(xn,wqkvt,qb,kpb,vpb,nullptr,nullptr,SCALE_Q,4096,3072,1024);
  attn_kernel<<<dim3(32,16,2),128,0,stream>>>(qb,kpb,vpb,ob);
  gemm_bt_kernel<1,64><<<dim3(8,64),256,0,stream>>>(ob,woutt,nullptr,nullptr,nullptr,out,b_out,1.f,4096,1024,1024);
}

// Round 8
// 170.882 us; speedup vs baseline: 1.1068x; 1.1068x over previous
//
#include <hip/hip_runtime.h>

typedef unsigned short u16;
typedef u16   u16x8 __attribute__((ext_vector_type(8)));
typedef __bf16 bf16x8 __attribute__((ext_vector_type(8)));
typedef float f32x4 __attribute__((ext_vector_type(4)));
typedef float f32x2 __attribute__((ext_vector_type(2)));
typedef _Float16 f16x4 __attribute__((ext_vector_type(4)));
typedef _Float16 f16x8 __attribute__((ext_vector_type(8)));
typedef unsigned u32x2 __attribute__((ext_vector_type(2)));
typedef unsigned u32x4 __attribute__((ext_vector_type(4)));

__device__ __forceinline__ u16 f2b(float f){ __bf16 h=(__bf16)f; return __builtin_bit_cast(u16,h); }

__device__ __forceinline__ float ex2(float x){
#if __has_builtin(__builtin_amdgcn_exp2f)
  return __builtin_amdgcn_exp2f(x);      // bare v_exp_f32, no libm range fixup
#else
  float r; asm("v_exp_f32 %0, %1" : "=v"(r) : "v"(x)); return r;
#endif
}

__device__ __forceinline__ f32x4 mfma16(u16x8 a, u16x8 b, f32x4 c){
  return __builtin_amdgcn_mfma_f32_16x16x32_bf16(
      __builtin_bit_cast(bf16x8,a), __builtin_bit_cast(bf16x8,b), c, 0,0,0);
}

__device__ __forceinline__ f32x4 mfma32h(f16x8 a, f16x8 b, f32x4 c){
  return __builtin_amdgcn_mfma_f32_16x16x32_f16(a, b, c, 0,0,0);
}

__device__ __forceinline__ void gl2lds16(const u16* g, u16* l){
  __builtin_amdgcn_global_load_lds((const __attribute__((address_space(1))) void*)g,
                                   (__attribute__((address_space(3))) void*)l, 16, 0, 0);
}

// ------------- prep: LN (blocks 0..4095) + weight transpose (4096..5119) -------------
__global__ __launch_bounds__(256) void prep_kernel(const float* __restrict__ x,
    const float* __restrict__ gamma, const float* __restrict__ beta, u16* __restrict__ xn,
    const float* __restrict__ wq, const float* __restrict__ wkv, const float* __restrict__ wout,
    u16* __restrict__ wqkvt, u16* __restrict__ woutt){
  __shared__ float tile[64][65];
  __shared__ float red[8];
  const int bid=blockIdx.x, t=threadIdx.x;
  if(bid<4096){
    const int row=bid;
    const float4 v = ((const float4*)(x + (size_t)row*1024))[t];
    float s  = v.x+v.y+v.z+v.w;
    float sq = v.x*v.x+v.y*v.y+v.z*v.z+v.w*v.w;
    for (int m=1;m<64;m<<=1){ s += __shfl_xor(s,m); sq += __shfl_xor(sq,m); }
    const int w=t>>6, l=t&63;
    if(l==0){ red[w]=s; red[4+w]=sq; }
    __syncthreads();
    const float S  = red[0]+red[1]+red[2]+red[3];
    const float SQ = red[4]+red[5]+red[6]+red[7];
    const float mu = S*(1.f/1024.f);
    const float var= SQ*(1.f/1024.f)-mu*mu;
    const float rs = rsqrtf(var+1e-5f);
    const float4 g4=((const float4*)gamma)[t], b4=((const float4*)beta)[t];
    u16 o0=f2b((v.x-mu)*rs*g4.x+b4.x);
    u16 o1=f2b((v.y-mu)*rs*g4.y+b4.y);
    u16 o2=f2b((v.z-mu)*rs*g4.z+b4.z);
    u16 o3=f2b((v.w-mu)*rs*g4.w+b4.w);
    uint2 p; p.x=(unsigned)o0|((unsigned)o1<<16); p.y=(unsigned)o2|((unsigned)o3<<16);
    ((uint2*)(xn + (size_t)row*1024))[t]=p;
    return;
  }
  const int wb=bid-4096;
  const int bx=wb&63, by=wb>>6;
  const float* in; u16* out; int C, cxx;
  if(bx<16){ in=wq;  out=wqkvt;           C=1024; cxx=bx; }
  else if(bx<48){ in=wkv; out=wqkvt+1024*1024; C=2048; cxx=bx-16; }
  else { in=wout; out=woutt;             C=1024; cxx=bx-48; }
  const int R=1024;
  const int c0=cxx*64, r0=by*64;
  {
    const int r=t>>2, cc=t&3;
    const float* gp = in + (size_t)(r0+r)*C + c0 + cc*16;
    #pragma unroll
    for(int i=0;i<4;i++){
      float4 f=((const float4*)gp)[i];
      tile[r][cc*16+i*4+0]=f.x; tile[r][cc*16+i*4+1]=f.y;
      tile[r][cc*16+i*4+2]=f.z; tile[r][cc*16+i*4+3]=f.w;
    }
  }
  __syncthreads();
  const int c=t>>2, rc=t&3;
  u16x8 a,b;
  #pragma unroll
  for(int i=0;i<8;i++) a[i]=f2b(tile[rc*16+i][c]);
  #pragma unroll
  for(int i=0;i<8;i++) b[i]=f2b(tile[rc*16+8+i][c]);
  u16* op = out + (size_t)(c0+c)*R + r0 + rc*16;
  *(u16x8*)op=a; *(u16x8*)(op+8)=b;
}

// --------------- GEMM: A bf16 [M,K] x Bt bf16 [N,K], tile TM x 128 -------------
// SWZ=1: XCD supertile for grid (24,32) — each XCD owns 12n x 8m (Bt 3MB + A 2MB L2-fit).
// SWZ=2: XCD m-chunk for grid (8,64) — each XCD owns all-n x 8m (A 2MB resident).
template<int MODE,int TM,int SWZ>
__global__ __launch_bounds__(256) void gemm_bt_kernel(const u16* __restrict__ A,
    const u16* __restrict__ Bt, u16* __restrict__ outQ, u16* __restrict__ outK,
    u16* __restrict__ outV, float* __restrict__ outF, const float* __restrict__ bias,
    float scale, int M, int N, int K){
  constexpr int MT = TM/32;           // acc m-tiles per wave
  __shared__ u16 As[TM*64];
  __shared__ u16 Bs[128*64];
  const int t=threadIdx.x, w=t>>6, l=t&63, qd=l>>4, ln=l&15;
  int bx, by;
  if(SWZ==1){      // grid (24,32): XCD k gets x in [ (k&1)*12, +12 ), y in [ (k>>1)*8, +8 )
    const int orig = blockIdx.x + 24*blockIdx.y;
    const int k=orig&7, s=orig>>3;
    bx=(k&1)*12 + s%12;
    by=(k>>1)*8 + s/12;
  } else if(SWZ==2){ // grid (8,64): XCD k gets all x, y in [k*8, k*8+8)
    const int orig = blockIdx.x + 8*blockIdx.y;
    const int k=orig&7, s=orig>>3;
    bx=s&7;
    by=k*8 + (s>>3);
  } else { bx=blockIdx.x; by=blockIdx.y; }
  const int m0=by*TM, n0=bx*128;
  const int wm=(w>>1)*(TM/2), wn=(w&1)*64;
  f32x4 acc[MT][4] = {};
  const int nK = K>>6;
  for(int kt=0; kt<nK; kt++){
    const int k0=kt*64;
    #pragma unroll
    for(int p=0;p<MT;p++){
      const int cid=p*256+t, r=cid>>3, pc=cid&7, g=pc^(r&7);
      gl2lds16(A + (size_t)(m0+r)*K + k0 + g*8, &As[(p*256 + (t&192))*8]);
    }
    #pragma unroll
    for(int p=0;p<4;p++){
      const int cid=p*256+t, r=cid>>3, pc=cid&7, g=pc^(r&7);
      gl2lds16(Bt + (size_t)(n0+r)*K + k0 + g*8, &Bs[(p*256 + (t&192))*8]);
    }
    __syncthreads();
    #pragma unroll
    for(int ks=0;ks<2;ks++){
      u16x8 af[MT], bf[4];
      #pragma unroll
      for(int mt=0;mt<MT;mt++){
        const int m=wm+mt*16+ln, kc=ks*4+qd, pcc=kc^(m&7);
        af[mt]=*(const u16x8*)&As[m*64 + pcc*8];
      }
      #pragma unroll
      for(int nt=0;nt<4;nt++){
        const int n=wn+nt*16+ln, kc=ks*4+qd, pcc=kc^(n&7);
        bf[nt]=*(const u16x8*)&Bs[n*64 + pcc*8];
      }
      #pragma unroll
      for(int mt=0;mt<MT;mt++)
        #pragma unroll
        for(int nt=0;nt<4;nt++)
          acc[mt][nt]=mfma16(af[mt],bf[nt],acc[mt][nt]);
    }
    __syncthreads();
  }
  if(MODE==1){
    #pragma unroll
    for(int mt=0;mt<MT;mt++)
      #pragma unroll
      for(int rr=0;rr<4;rr++){
        const int row = m0+wm+mt*16+qd*4+rr;
        #pragma unroll
        for(int nt=0;nt<4;nt++){
          const int col = n0+wn+nt*16+ln;
          outF[(size_t)row*N+col]=acc[mt][nt][rr]+bias[col];
        }
      }
  } else if(n0<1024){
    #pragma unroll
    for(int mt=0;mt<MT;mt++)
      #pragma unroll
      for(int rr=0;rr<4;rr++){
        const int row = m0+wm+mt*16+qd*4+rr;
        #pragma unroll
        for(int nt=0;nt<4;nt++)
          outQ[(size_t)row*1024 + n0+wn+nt*16+ln]=f2b(acc[mt][nt][rr]*scale);
      }
  } else if(n0<2048){
    // K packed per-head: head is wave-uniform; d = nt*16+ln
    u16* kp = outK + (size_t)((m0>>11)*16 + ((n0-1024+wn)>>6))*131072;
    const int jb = (m0&2047) + wm;
    #pragma unroll
    for(int mt=0;mt<MT;mt++)
      #pragma unroll
      for(int rr=0;rr<4;rr++){
        const int j = jb + mt*16 + qd*4 + rr;
        #pragma unroll
        for(int nt=0;nt<4;nt++)
          kp[(size_t)j*64 + nt*16+ln]=f2b(acc[mt][nt][rr]);
      }
  } else {
    // V packed fp16 [j/32][(j>>3)&3][d 64][j&7]: lane writes 4 j-consecutive f16 = uint2
    u16* vpp = outV + (size_t)((m0>>11)*16 + ((n0-2048+wn)>>6))*131072;
    const int jb = (m0&2047) + wm;
    #pragma unroll
    for(int mt=0;mt<MT;mt++){
      const int j = jb + mt*16 + qd*4;                  // + rr (0..3)
      const int grp = (j>>5)*4 + ((j>>3)&3);            // wave-uniform per (mt,qd)
      const int sub = j&7;                              // = (qd&1)*4
      #pragma unroll
      for(int nt=0;nt<4;nt++){
        const auto lo=__builtin_amdgcn_cvt_pkrtz(acc[mt][nt][0],acc[mt][nt][1]);
        const auto hi=__builtin_amdgcn_cvt_pkrtz(acc[mt][nt][2],acc[mt][nt][3]);
        uint2 w2; w2.x=__builtin_bit_cast(unsigned,lo); w2.y=__builtin_bit_cast(unsigned,hi);
        *(uint2*)&vpp[(size_t)(grp*64 + nt*16+ln)*8 + sub] = w2;
      }
    }
  }
}

// ------------------ flash attention (S^T, fixed-base softmax, BQ=256) ------------------
// Q bf16 [b,2048,1024] (scale*log2e folded), Kp bf16 [b,h,2048,64] packed,
// Vp fp16 [b,h,j/32,(j>>3)&3,d 64,j&7], O bf16 [b,2048,1024].
// Round-7: R4 structure (best measured: 45.7us) + XCD-grouped 1D grid.
// bid = (g&7) + 8*qt + 64*(g>>3), g=h+16*bb: all 8 qt-blocks of one (h,bb) land
// on XCD g&7 (dispatch round-robins bid%8) -> KV (512KB/group, 4 groups = 2MB)
// becomes L2-resident; stage drains hit L2 (~200cy) not fabric (~900cy);
// FETCH_SIZE should drop ~70MB -> ~30MB.
__global__ __launch_bounds__(512,4) void attn_kernel(const u16* __restrict__ Q,
    const u16* __restrict__ Kp, const u16* __restrict__ Vp, u16* __restrict__ O){
  __shared__ u16 Ks[2][8192];   // 2x16KB: K tile [128 j][64 d], permuted rows + xor swizzle
  __shared__ u16 Vs[2][8192];   // 2x16KB: Vp block [4 j32][4 j8grp][64 d][8], contiguous
  const int bid=blockIdx.x;
  const int g=(bid&7) + 8*(bid>>6);     // group = h + 16*bb, wave... XCD-uniform
  const int qt=(bid>>3)&7;
  const int h=g&15, bb=g>>4;
  const int t=threadIdx.x, w=t>>6, l=t&63, qd=l>>4, ln=l&15;
  const int q0=qt*256;
  const size_t baseQ=(size_t)bb*2048*1024 + h*64;
  const size_t baseKV=(size_t)(bb*16+h)*131072;
  u16x8 qf[2][2];
  #pragma unroll
  for(int sub=0;sub<2;sub++)
    #pragma unroll
    for(int ks=0;ks<2;ks++)
      qf[sub][ks] = *(const u16x8*)(Q + baseQ + (size_t)(q0+w*32+sub*16+ln)*1024 + ks*32+qd*8);
  f32x4 o_acc[2][4]={};
  f32x4 l_acc[2]={};
  const f16x8 onesB={(_Float16)1.f,(_Float16)1.f,(_Float16)1.f,(_Float16)1.f,
                     (_Float16)1.f,(_Float16)1.f,(_Float16)1.f,(_Float16)1.f};
  const f32x4 zf={0.f,0.f,0.f,0.f};

  // precomputed K staging source offsets: row-permutation + xor chunk swizzle
  int koff[2];
  #pragma unroll
  for(int p=0;p<2;p++){
    const int r=(p*512+t)>>3, gg=(t&7)^(r&7);
    const int pr=(r&~31)+((r>>2)&3)*8+((r>>4)&1)*4+(r&3);
    koff[p]=pr*64+gg*8;
  }

  // stage the 128-row K tile (permuted rows) + matching V block at row j0 into buf
  auto stage=[&](int buf,int j0){
    #pragma unroll
    for(int p=0;p<2;p++)
      gl2lds16(Kp + baseKV + (size_t)j0*64 + koff[p], &Ks[buf][(p*512+(t&448))*8]);
    #pragma unroll
    for(int p=0;p<2;p++)  // Vp: contiguous 16KB block (4 j32 groups)
      gl2lds16(Vp + baseKV + (size_t)(j0>>5)*2048 + (size_t)(p*512+t)*8,
               &Vs[buf][(p*512+(t&448))*8]);
  };

  stage(0,0);
  __syncthreads();             // prologue tile landed
  int cur=0;
  for(int jt=0;jt<16;jt++){
    if(jt<15) stage(cur^1,(jt+1)*128);   // async prefetch; drains at loop-end barrier
    const u16* Kb=&Ks[cur][0];
    const u16* Vb=&Vs[cur][0];
    #pragma unroll
    for(int jh=0;jh<2;jh++){
      // S^T for both q-subtiles; one kf read serves both (LDS amortization)
      f32x4 s[2][4];
      #pragma unroll
      for(int ks=0;ks<2;ks++){
        u16x8 kf[4];
        #pragma unroll
        for(int j4=0;j4<4;j4++)
          kf[j4]=*(const u16x8*)&Kb[((jh*4+j4)*16+ln)*64 + (((ks*4+qd)^(ln&7))*8)];
        __builtin_amdgcn_s_setprio(1);
        #pragma unroll
        for(int j4=0;j4<4;j4++){
          s[0][j4] = ks? mfma16(kf[j4],qf[0][1],s[0][j4]) : mfma16(kf[j4],qf[0][0],zf);
          s[1][j4] = ks? mfma16(kf[j4],qf[1][1],s[1][j4]) : mfma16(kf[j4],qf[1][0],zf);
        }
        __builtin_amdgcn_s_setprio(0);
      }
      // P = exp2(s); one V read serves both subtiles' PV; l via ones-MFMA
      #pragma unroll
      for(int al=0;al<2;al++){
        const int a=jh*2+al;             // j32 group
        f16x8 vv[4];
        #pragma unroll
        for(int dt=0;dt<4;dt++)
          vv[dt]=*(const f16x8*)&Vb[((a*4+qd)*64 + dt*16+ln)*8];
        #pragma unroll
        for(int sub=0;sub<2;sub++){
          const int t0=al*2, t1=al*2+1;
          u32x4 pw;
          pw.x=__builtin_bit_cast(unsigned,__builtin_amdgcn_cvt_pkrtz(ex2(s[sub][t0][0]),ex2(s[sub][t0][1])));
          pw.y=__builtin_bit_cast(unsigned,__builtin_amdgcn_cvt_pkrtz(ex2(s[sub][t0][2]),ex2(s[sub][t0][3])));
          pw.z=__builtin_bit_cast(unsigned,__builtin_amdgcn_cvt_pkrtz(ex2(s[sub][t1][0]),ex2(s[sub][t1][1])));
          pw.w=__builtin_bit_cast(unsigned,__builtin_amdgcn_cvt_pkrtz(ex2(s[sub][t1][2]),ex2(s[sub][t1][3])));
          const f16x8 pf=__builtin_bit_cast(f16x8,pw);
          __builtin_amdgcn_s_setprio(1);
          l_acc[sub]=mfma32h(pf,onesB,l_acc[sub]);
          #pragma unroll
          for(int dt=0;dt<4;dt++)
            o_acc[sub][dt]=mfma32h(pf,vv[dt],o_acc[sub][dt]);
          __builtin_amdgcn_s_setprio(0);
        }
      }
    }
    __syncthreads();        // prefetch landed; buf[cur] free for next stage
    cur^=1;
  }

  // l_acc[sub][rr] = sum_j P (same across ln) -> direct normalize
  #pragma unroll
  for(int sub=0;sub<2;sub++)
    #pragma unroll
    for(int rr=0;rr<4;rr++){
      const float lr=1.f/l_acc[sub][rr];
      const int row=q0+w*32+sub*16+qd*4+rr;
      #pragma unroll
      for(int dt=0;dt<4;dt++)
        O[baseQ + (size_t)row*1024 + dt*16+ln]=f2b(o_acc[sub][dt][rr]*lr);
    }
}

extern "C" void kernel_launch(void* const* d_in, const int* in_sizes, int n_in,
                              void* d_out, int out_size, void* d_ws, size_t ws_size,
                              hipStream_t stream) {
  const float* x     = (const float*)d_in[0];
  const float* w_q   = (const float*)d_in[1];
  const float* w_kv  = (const float*)d_in[2];
  const float* w_out = (const float*)d_in[3];
  const float* b_out = (const float*)d_in[4];
  const float* gamma = (const float*)d_in[5];
  const float* beta  = (const float*)d_in[6];
  float* out = (float*)d_out;

  char* ws=(char*)d_ws;
  size_t off=0;
  u16* xn    =(u16*)(ws+off); off += (size_t)4096*1024*2;
  u16* wqkvt =(u16*)(ws+off); off += (size_t)3072*1024*2;
  u16* woutt =(u16*)(ws+off); off += (size_t)1024*1024*2;
  u16* qb    =(u16*)(ws+off); off += (size_t)4096*1024*2;
  u16* kpb   =(u16*)(ws+off); off += (size_t)4096*1024*2;
  u16* vpb   =(u16*)(ws+off); off += (size_t)4096*1024*2;
  u16* ob    =(u16*)(ws+off); off += (size_t)4096*1024*2;

  prep_kernel<<<5120,256,0,stream>>>(x,gamma,beta,xn,w_q,w_kv,w_out,wqkvt,woutt);

  const float SCALE_Q = 0.125f*1.4426950408889634f; // 1/sqrt(64) * log2(e)
  gemm_bt_kernel<2,128,1><<<dim3(24,32),256,0,stream>>>(xn,wqkvt,qb,kpb,vpb,nullptr,nullptr,SCALE_Q,4096,3072,1024);
  attn_kernel<<<dim3(256),512,0,stream>>>(qb,kpb,vpb,ob);
  gemm_bt_kernel<1,64,2><<<dim3(8,64),256,0,stream>>>(ob,woutt,nullptr,nullptr,nullptr,out,b_out,1.f,4096,1024,1024);
}